// Round 12
// baseline (190.681 us; speedup 1.0000x reference)
//
#include <hip/hip_runtime.h>
#include <cstdint>
#include <cstddef>

#define NG 3
#define NB 32
#define NT 1024
#define ND 512
#define NU 512
#define PLANE (NG * NB * NT)                        // 98304: one nq partial plane

typedef __bf16 bf16x8 __attribute__((ext_vector_type(8)));
typedef float  f32x16 __attribute__((ext_vector_type(16)));

static __device__ __forceinline__ unsigned int f2bf(float f) {
    union { float f; unsigned int u; } v; v.f = f;
    return (v.u + 0x7FFFu + ((v.u >> 16) & 1u)) >> 16;   // RNE f32->bf16
}
static __device__ __forceinline__ float bf2f(unsigned short h) {
    union { float f; unsigned int u; } v; v.u = ((unsigned int)h) << 16;
    return v.f;
}
static __device__ __forceinline__ unsigned int cvt_pk_bf16(float lo, float hi) {
    unsigned int r;
    asm("v_cvt_pk_bf16_f32 %0, %1, %2" : "=v"(r) : "v"(lo), "v"(hi));
    return r;
}
static __device__ __forceinline__ bf16x8 ld_bf16x8(const char* base, int off) {
    return __builtin_bit_cast(bf16x8, *(const uint4*)(base + off));
}

#define AS1(p) ((const __attribute__((address_space(1))) void*)(p))
#define AS3(p) ((__attribute__((address_space(3))) void*)(p))

// ---------- kernel 1: qb[g,b,u] = sum_d query[g,b,d]*W1[g,d,u] + b1 + b2 ----------
__global__ __launch_bounds__(256) void prep_qb_kernel(
    const float* __restrict__ query, const float* __restrict__ W1,
    const float* __restrict__ b1, const float* __restrict__ b2,
    float* __restrict__ qb)
{
    __shared__ float qs[NB][ND];                    // 64 KiB
    const int g  = blockIdx.x >> 3;
    const int uc = blockIdx.x & 7;
    const int tid = threadIdx.x;

    const float4* qsrc = (const float4*)(query + (size_t)g * NB * ND);
    #pragma unroll
    for (int i = 0; i < 16; ++i)
        ((float4*)&qs[0][0])[tid + i * 256] = qsrc[tid + i * 256];
    __syncthreads();

    const int u  = uc * 64 + (tid & 63);
    const int b0 = tid >> 6;                        // 0..3
    float acc[8] = {};
    const float* w1col = W1 + (size_t)g * ND * NU + u;
    for (int d = 0; d < ND; ++d) {
        float w = w1col[(size_t)d * NU];            // coalesced over u
        #pragma unroll
        for (int j = 0; j < 8; ++j)
            acc[j] = fmaf(qs[b0 + 4 * j][d], w, acc[j]);  // LDS broadcast
    }
    const float bias = b1[g * NU + u] + b2[g * NU + u];
    #pragma unroll
    for (int j = 0; j < 8; ++j)
        qb[((size_t)g * NB + (b0 + 4 * j)) * NU + u] = acc[j] + bias;
}

// ---------- kernel 2: w2t = k-major bf16 image of W2^T ----------
// Panel per (g, nq): [64 kgrp][128 u][8 bf16] = 128 KiB. A wave's B-frag read
// (32 lanes x 16B at consecutive u) is 512B contiguous -> ZERO bank conflicts.
// Image is LDS-linear: staged with plain sequential global_load_lds.
__global__ __launch_bounds__(256) void prep_w2t_kernel(
    const float* __restrict__ W2, unsigned short* __restrict__ w2t)
{
    __shared__ float tile[64][65];                  // +1 pad: conflict-free transpose
    const int g  = blockIdx.x >> 6;
    const int tb = blockIdx.x & 63;
    const int d0 = (tb >> 3) * 64;
    const int u0 = (tb & 7) * 64;
    const int tx = threadIdx.x & 63;
    const int ty = threadIdx.x >> 6;

    const float* src = W2 + (size_t)g * ND * NU;
    #pragma unroll
    for (int k = 0; k < 16; ++k) {
        int r = ty + 4 * k;
        tile[r][tx] = src[(size_t)(d0 + r) * NU + (u0 + tx)];   // tile[d_loc][u_loc]
    }
    __syncthreads();
    #pragma unroll
    for (int k = 0; k < 16; ++k) {
        int ul = ty + 4 * k;
        int u  = u0 + ul;                           // output unit
        int d  = d0 + tx;                           // k index
        unsigned short h = (unsigned short)f2bf(tile[tx][ul]);  // = W2[d][u]
        int nq = u >> 7, u_l = u & 127, kg = d >> 3, e = d & 7;
        size_t off_el = ((size_t)(g * 4 + nq) << 16)            // 65536 ushort/panel
                      + (size_t)((kg << 10) + (u_l << 3) + e);
        w2t[off_el] = h;
    }
}

// ======== score helpers ========
#define COMPUTE(AV_, KS_) do {                                                 \
    const int _kb = ((KS_) << 14) + bconst;                                    \
    _Pragma("unroll")                                                          \
    for (int _kf = 0; _kf < 4; ++_kf) {                                        \
        union { bf16x8 v; unsigned int u[4]; } _t;                             \
        _t.u[0] = cvt_pk_bf16((AV_)[2*_kf].x,   (AV_)[2*_kf].y);               \
        _t.u[1] = cvt_pk_bf16((AV_)[2*_kf].z,   (AV_)[2*_kf].w);               \
        _t.u[2] = cvt_pk_bf16((AV_)[2*_kf+1].x, (AV_)[2*_kf+1].y);             \
        _t.u[3] = cvt_pk_bf16((AV_)[2*_kf+1].z, (AV_)[2*_kf+1].w);             \
        bf16x8 _b0 = ld_bf16x8(Bsc, _kb + (_kf << 12));                        \
        bf16x8 _b1 = ld_bf16x8(Bsc, _kb + (_kf << 12) + 512);                  \
        bf16x8 _b2 = ld_bf16x8(Bsc, _kb + (_kf << 12) + 1024);                 \
        bf16x8 _b3 = ld_bf16x8(Bsc, _kb + (_kf << 12) + 1536);                 \
        acc0 = __builtin_amdgcn_mfma_f32_32x32x16_bf16(_t.v, _b0, acc0, 0, 0, 0); \
        acc1 = __builtin_amdgcn_mfma_f32_32x32x16_bf16(_t.v, _b1, acc1, 0, 0, 0); \
        acc2 = __builtin_amdgcn_mfma_f32_32x32x16_bf16(_t.v, _b2, acc2, 0, 0, 0); \
        acc3 = __builtin_amdgcn_mfma_f32_32x32x16_bf16(_t.v, _b3, acc3, 0, 0, 0); \
    }                                                                          \
} while (0)

#define LOADA(AV_, MT_, KS_) do {                                             \
    const float* _ap = abase + (MT_) * 131072 + ((KS_) << 6);                 \
    _Pragma("unroll")                                                         \
    for (int _kf = 0; _kf < 4; ++_kf) {                                       \
        const float4* _p = (const float4*)(_ap + (_kf << 4));                 \
        (AV_)[2*_kf] = _p[0]; (AV_)[2*_kf+1] = _p[1];                         \
    }                                                                         \
} while (0)

#define EPI_UT(ACC_, UT_) do {                                                \
    _Pragma("unroll")                                                         \
    for (int _r = 0; _r < 16; ++_r) {                                         \
        float _x = (ACC_)[_r] + qv[UT_];                                      \
        float _e = exp2f(2.8853900817779268f * _x);                           \
        float _t = 1.0f - 2.0f * __builtin_amdgcn_rcpf(_e + 1.0f);            \
        p[_r] = fmaf(_t, vv[UT_], p[_r]);                                     \
    }                                                                         \
} while (0)

// ---------- kernel 3: fused score, B-panel-resident, BARRIER-FREE loop ----------
// Block: 512 thr (8 waves), m = 512 t-rows (2 m-tiles of 256), n = 128 u.
// B panel (128u x 512k bf16 = 128 KiB) loaded ONCE; qb/V slices in LDS.
// Loop: per wave-slice {issue next A-loads (regs, 1 ahead); cvt; 16 conflict-
// free ds_read; 16 MFMA}. No barriers, no in-loop staging, no manual waits.
// Epilogue per m-tile: tanh + V-dot + u-reduce -> bf16 partial (nq plane).
__global__ __launch_bounds__(512) void score_kernel(
    const float* __restrict__ values, const unsigned short* __restrict__ w2t,
    const float* __restrict__ qbg, const float* __restrict__ Vvec,
    unsigned short* __restrict__ parts)
{
    __shared__ char  Bs[131072];                    // 128 KiB B panel
    __shared__ float qbs[128];
    __shared__ float Vs[128];

    const int blk  = blockIdx.x;
    const int g    = blk >> 8;                      // 256 blocks per g
    const int rem  = blk & 255;
    const int b    = rem >> 3;
    const int th   = (rem >> 2) & 1;                // t half (512 rows)
    const int nq   = rem & 3;                       // u quarter (128)
    const int tid  = threadIdx.x;
    const int lane = tid & 63;
    const int wave = tid >> 6;
    const int rl   = lane & 31;
    const int hi   = lane >> 5;

    // ---- stage B panel (linear DMA), qb/V slices ----
    const char* bimg = (const char*)w2t + ((size_t)(g * 4 + nq) << 17);
    #pragma unroll
    for (int ps = 0; ps < 16; ++ps)
        __builtin_amdgcn_global_load_lds(AS1(bimg + (ps << 13) + (tid << 4)),
                                         AS3(Bs + (ps << 13) + (tid << 4)), 16, 0, 0);
    if (wave < 2) {
        const float* qsrc = qbg + (((size_t)(g * NB + b)) << 9) + (nq << 7) + (wave << 6) + lane;
        __builtin_amdgcn_global_load_lds(AS1(qsrc), AS3(&qbs[(wave << 6) + lane]), 4, 0, 0);
    } else if (wave < 4) {
        const float* vsrc = Vvec + (g << 9) + (nq << 7) + ((wave - 2) << 6) + lane;
        __builtin_amdgcn_global_load_lds(AS1(vsrc), AS3(&Vs[((wave - 2) << 6) + lane]), 4, 0, 0);
    }

    // ---- A base: wave owns 32 rows per m-tile; lane reads 8 floats per kf ----
    const float* abase = values
        + (((size_t)(g * NB + b) * NT) + th * 512 + (wave << 5) + rl) * ND + (hi << 3);

    float4 av0[8], av1[8];
    LOADA(av0, 0, 0);                               // slice 0

    asm volatile("s_waitcnt vmcnt(0) lgkmcnt(0)" ::: "memory");
    __builtin_amdgcn_s_barrier();                   // the ONLY block barrier

    float qv[4], vv[4];
    #pragma unroll
    for (int ut = 0; ut < 4; ++ut) {
        qv[ut] = qbs[(ut << 5) + rl];
        vv[ut] = Vs[(ut << 5) + rl];
    }

    const char* Bsc = Bs;
    const int bconst = (hi << 11) + (rl << 4);      // hi*2048 + rl*16

    f32x16 acc0 = (f32x16)(0.0f), acc1 = (f32x16)(0.0f);
    f32x16 acc2 = (f32x16)(0.0f), acc3 = (f32x16)(0.0f);

    unsigned short* prow = parts + (size_t)nq * PLANE + ((size_t)(g * NB + b)) * NT;

    #pragma unroll 1
    for (int s2 = 0; s2 < 8; ++s2) {                // 2 slices per iter, 16 total
        const int mt  = s2 >> 2;
        const int ksE = (2 * s2) & 7;
        const int ksO = ksE + 1;

        // even slice: consume av0, prefetch av1 for odd slice
        LOADA(av1, mt, ksO);
        COMPUTE(av0, ksE);

        // odd slice: consume av1, prefetch av0 for next even slice
        if (s2 < 7) {
            const int mtN = (s2 + 1) >> 2;
            const int ksN = (2 * s2 + 2) & 7;
            LOADA(av0, mtN, ksN);
        }
        COMPUTE(av1, ksO);

        if (s2 == 3 || s2 == 7) {                   // end of m-tile: epilogue
            float p[16] = {};
            EPI_UT(acc0, 0); EPI_UT(acc1, 1); EPI_UT(acc2, 2); EPI_UT(acc3, 3);
            #pragma unroll
            for (int r = 0; r < 16; ++r) {
                float v = p[r];
                v += __shfl_xor(v, 1);
                v += __shfl_xor(v, 2);
                v += __shfl_xor(v, 4);
                v += __shfl_xor(v, 8);
                v += __shfl_xor(v, 16);
                p[r] = v;
            }
            if (rl == 0) {
                const int trow = th * 512 + mt * 256 + (wave << 5) + 4 * hi;
                #pragma unroll
                for (int r = 0; r < 16; ++r)
                    prow[trow + (r & 3) + 8 * (r >> 2)] = (unsigned short)f2bf(p[r]);
            }
            acc0 = (f32x16)(0.0f); acc1 = (f32x16)(0.0f);
            acc2 = (f32x16)(0.0f); acc3 = (f32x16)(0.0f);
        }
    }
}

// ---------- kernel 4: softmax over T + context, 4 d-slices per (g,b) ----------
__global__ __launch_bounds__(256) void finish_kernel(
    const unsigned short* __restrict__ parts, const float* __restrict__ bV,
    const float* __restrict__ values,
    float* __restrict__ out_ctx, float* __restrict__ out_w)
{
    __shared__ float sl[NT];
    __shared__ float red[16];
    __shared__ float cred[4][128];
    const int blk   = blockIdx.x;
    const int gb    = blk >> 2;                     // 0..95
    const int slice = blk & 3;                      // d-slice of 128
    const int tid = threadIdx.x;
    const int lane = tid & 63, wid = tid >> 6;
    const float bv = bV[gb >> 5];

    float s[4];
    #pragma unroll
    for (int j = 0; j < 4; ++j) {
        size_t idx = (size_t)gb * NT + tid + 256 * j;
        s[j] = bf2f(parts[idx]) + bf2f(parts[idx + PLANE])
             + bf2f(parts[idx + 2 * PLANE]) + bf2f(parts[idx + 3 * PLANE]) + bv;
    }

    float m = fmaxf(fmaxf(s[0], s[1]), fmaxf(s[2], s[3]));
    #pragma unroll
    for (int mask = 32; mask; mask >>= 1) m = fmaxf(m, __shfl_xor(m, mask));
    if (lane == 0) red[wid] = m;
    __syncthreads();
    const float gm = fmaxf(fmaxf(red[0], red[1]), fmaxf(red[2], red[3]));

    float e[4], ps = 0.f;
    #pragma unroll
    for (int j = 0; j < 4; ++j) { e[j] = __expf(s[j] - gm); ps += e[j]; }
    #pragma unroll
    for (int mask = 32; mask; mask >>= 1) ps += __shfl_xor(ps, mask);
    if (lane == 0) red[8 + wid] = ps;
    __syncthreads();
    const float inv = 1.f / (red[8] + red[9] + red[10] + red[11]);

    #pragma unroll
    for (int j = 0; j < 4; ++j) {
        float w = e[j] * inv;
        sl[tid + 256 * j] = w;
        if (slice == 0) out_w[(size_t)gb * NT + tid + 256 * j] = w;
    }
    __syncthreads();

    const int dp = tid & 63;
    const int tg = tid >> 6;
    const float* vbase = values + (size_t)gb * NT * ND + slice * 128 + dp * 2;
    float ax = 0.f, ay = 0.f;
    #pragma unroll 4
    for (int t = tg; t < NT; t += 4) {
        float2 v = *(const float2*)(vbase + (size_t)t * ND);
        float w = sl[t];
        ax = fmaf(w, v.x, ax);
        ay = fmaf(w, v.y, ay);
    }
    cred[tg][dp * 2]     = ax;
    cred[tg][dp * 2 + 1] = ay;
    __syncthreads();
    if (tid < 128) {
        float r = cred[0][tid] + cred[1][tid] + cred[2][tid] + cred[3][tid];
        out_ctx[(size_t)gb * ND + slice * 128 + tid] = r;
    }
}

extern "C" void kernel_launch(void* const* d_in, const int* in_sizes, int n_in,
                              void* d_out, int out_size, void* d_ws, size_t ws_size,
                              hipStream_t stream)
{
    (void)in_sizes; (void)n_in; (void)out_size; (void)ws_size;
    const float* query  = (const float*)d_in[0];
    const float* values = (const float*)d_in[1];
    const float* W1     = (const float*)d_in[2];
    const float* b1     = (const float*)d_in[3];
    const float* W2     = (const float*)d_in[4];
    const float* b2     = (const float*)d_in[5];
    const float* Vv     = (const float*)d_in[6];
    const float* bV     = (const float*)d_in[7];

    float* out_ctx = (float*)d_out;
    float* out_w   = out_ctx + (size_t)NG * NB * ND;

    // ws: qb fp32 192 KiB | parts bf16 4 planes 768 KiB | w2t image 1.5 MiB
    float* qb = (float*)d_ws;
    unsigned short* parts = (unsigned short*)(qb + (size_t)NG * NB * NU);
    unsigned short* w2t   = parts + (size_t)4 * PLANE;

    prep_qb_kernel <<<NG * 8,      256, 0, stream>>>(query, W1, b1, b2, qb);
    prep_w2t_kernel<<<NG * 64,     256, 0, stream>>>(W2, w2t);
    score_kernel   <<<NG * 256,    512, 0, stream>>>(values, w2t, qb, Vv, parts);
    finish_kernel  <<<NG * NB * 4, 256, 0, stream>>>(parts, bV, values, out_ctx, out_w);
}

// Round 13
// 159.420 us; speedup vs baseline: 1.1961x; 1.1961x over previous
//
#include <hip/hip_runtime.h>
#include <cstdint>
#include <cstddef>

#define NG 3
#define NB 32
#define NT 1024
#define ND 512
#define NU 512

typedef __bf16 bf16x8 __attribute__((ext_vector_type(8)));
typedef float  f32x4  __attribute__((ext_vector_type(4)));

static __device__ __forceinline__ unsigned int f2bf(float f) {
    union { float f; unsigned int u; } v; v.f = f;
    return (v.u + 0x7FFFu + ((v.u >> 16) & 1u)) >> 16;   // RNE f32->bf16
}
static __device__ __forceinline__ unsigned int cvt_pk_bf16(float lo, float hi) {
    unsigned int r;
    asm("v_cvt_pk_bf16_f32 %0, %1, %2" : "=v"(r) : "v"(lo), "v"(hi));
    return r;
}
static __device__ __forceinline__ bf16x8 ld_bf16x8(const char* base, int off) {
    return __builtin_bit_cast(bf16x8, *(const uint4*)(base + off));
}

#define AS1(p) ((const __attribute__((address_space(1))) void*)(p))
#define AS3(p) ((__attribute__((address_space(3))) void*)(p))

// ---------- kernel 1: qb[g,b,u] = sum_d query[g,b,d]*W1[g,d,u] + b1 + b2 ----------
__global__ __launch_bounds__(256) void prep_qb_kernel(
    const float* __restrict__ query, const float* __restrict__ W1,
    const float* __restrict__ b1, const float* __restrict__ b2,
    float* __restrict__ qb)
{
    __shared__ float qs[NB][ND];                    // 64 KiB
    const int g  = blockIdx.x >> 3;
    const int uc = blockIdx.x & 7;
    const int tid = threadIdx.x;

    const float4* qsrc = (const float4*)(query + (size_t)g * NB * ND);
    #pragma unroll
    for (int i = 0; i < 16; ++i)
        ((float4*)&qs[0][0])[tid + i * 256] = qsrc[tid + i * 256];
    __syncthreads();

    const int u  = uc * 64 + (tid & 63);
    const int b0 = tid >> 6;                        // 0..3
    float acc[8] = {};
    const float* w1col = W1 + (size_t)g * ND * NU + u;
    for (int d = 0; d < ND; ++d) {
        float w = w1col[(size_t)d * NU];            // coalesced over u
        #pragma unroll
        for (int j = 0; j < 8; ++j)
            acc[j] = fmaf(qs[b0 + 4 * j][d], w, acc[j]);  // LDS broadcast
    }
    const float bias = b1[g * NU + u] + b2[g * NU + u];
    #pragma unroll
    for (int j = 0; j < 8; ++j)
        qb[((size_t)g * NB + (b0 + 4 * j)) * NU + u] = acc[j] + bias;
}

// ---------- kernel 2: w2t = DMA-ready bf16 image of W2^T for 16x16x32 frags ----
// 8 KiB chunk keyed by (g, uc=u>>5, kq=d>>7). In-chunk (conflict-free k-major):
// [kk32=(d>>5)&3][nf=(u&31)>>4][u16=u&15][kgrp=(d>>3)&3][e=d&7] * 2B.
// Wave B-frag read: lane addr (l&15)*64 + (l>>4)*16 -> 1 KiB contiguous.
__global__ __launch_bounds__(256) void prep_w2t_kernel(
    const float* __restrict__ W2, char* __restrict__ w2t)
{
    __shared__ float tile[64][65];                  // +1 pad: conflict-free transpose
    const int g  = blockIdx.x >> 6;
    const int tb = blockIdx.x & 63;
    const int d0 = (tb >> 3) * 64;
    const int u0 = (tb & 7) * 64;
    const int tx = threadIdx.x & 63;
    const int ty = threadIdx.x >> 6;

    const float* src = W2 + (size_t)g * ND * NU;
    #pragma unroll
    for (int k = 0; k < 16; ++k) {
        int r = ty + 4 * k;
        tile[r][tx] = src[(size_t)(d0 + r) * NU + (u0 + tx)];   // tile[d_loc][u_loc]
    }
    __syncthreads();
    #pragma unroll
    for (int k = 0; k < 16; ++k) {
        int ul = ty + 4 * k;
        int u  = u0 + ul;
        int d  = d0 + tx;
        unsigned short h = (unsigned short)f2bf(tile[tx][ul]);  // = W2[d][u]
        int uc   = u >> 5, u32 = u & 31;
        int nf   = u32 >> 4, u16 = u32 & 15;
        int kq   = d >> 7, kk32 = (d >> 5) & 3, kgrp = (d >> 3) & 3, e = d & 7;
        size_t off = ((size_t)((g * 16 + uc) * 4 + kq) << 13)
                   + (size_t)((kk32 << 11) + (nf << 10) + (u16 << 6) + (kgrp << 4) + (e << 1));
        *(unsigned short*)(w2t + off) = h;
    }
}

// ---------- kernel 3: fused score, 16x16x32, 4 blocks/CU occupancy design ----
// 256 thr (4 waves); wave owns 16 t-rows; A in 64 regs (16 bf16x8, static idx).
// B streamed through ring-3 of 8 KiB chunks (32u x 128k), counted vmcnt(2).
// launch_bounds(256,4): cap 128 regs -> 4 waves/SIMD (the occupancy cliff).
__global__ __launch_bounds__(256, 4) void score_kernel(
    const float* __restrict__ values, const char* __restrict__ w2t,
    const float* __restrict__ qbg, const float* __restrict__ Vvec,
    float* __restrict__ scores)
{
    __shared__ char  Bs[3][8192];                   // 24 KiB ring
    __shared__ float qbs[NU];
    __shared__ float Vs[NU];

    const int blk  = blockIdx.x;
    const int g    = blk >> 9;                      // 512 blocks per g
    const int rem  = blk & 511;
    const int b    = rem >> 4;
    const int t0   = (rem & 15) << 6;               // 16 tiles of 64 rows
    const int tid  = threadIdx.x;
    const int lane = tid & 63;
    const int wave = tid >> 6;
    const int row16 = lane & 15;
    const int kg    = lane >> 4;                    // 0..3

    const char* w2g = w2t + ((size_t)g << 19);      // g * 512 KiB (64 chunks)

    // stage 8 KiB chunk ph (= uc*4+kq) into buf: 2 x 16B per thread, linear
    auto stage = [&](int ph, char* buf) {
        const char* src = w2g + ((size_t)ph << 13) + (tid << 4);
        __builtin_amdgcn_global_load_lds(AS1(src),        AS3(buf + (tid << 4)),        16, 0, 0);
        __builtin_amdgcn_global_load_lds(AS1(src + 4096), AS3(buf + (tid << 4) + 4096), 16, 0, 0);
    };

    {   // qb(+biases) and V via LDS-DMA
        const float* qsrc = qbg + ((size_t)(g * NB + b)) * NU;
        const float* vsrc = Vvec + (size_t)g * NU;
        __builtin_amdgcn_global_load_lds(AS1(qsrc + tid),       AS3(&qbs[tid]),       4, 0, 0);
        __builtin_amdgcn_global_load_lds(AS1(qsrc + tid + 256), AS3(&qbs[tid + 256]), 4, 0, 0);
        __builtin_amdgcn_global_load_lds(AS1(vsrc + tid),       AS3(&Vs[tid]),        4, 0, 0);
        __builtin_amdgcn_global_load_lds(AS1(vsrc + tid + 256), AS3(&Vs[tid + 256]),  4, 0, 0);
    }
    stage(0, Bs[0]);
    stage(1, Bs[1]);

    // ---- A panel -> 16 bf16x8 regs: lane holds A[t0+wave*16+row16][kk*32+kg*8+e]
    bf16x8 afrag[16];
    {
        const float* aptr = values
            + ((size_t)((g * NB + b) * NT + t0 + (wave << 4) + row16)) * ND + (kg << 3);
        #pragma unroll
        for (int kk = 0; kk < 16; ++kk) {
            const float4* p4 = (const float4*)(aptr + (kk << 5));
            float4 v0 = p4[0], v1 = p4[1];
            union { bf16x8 v; unsigned int u[4]; } t;
            t.u[0] = cvt_pk_bf16(v0.x, v0.y);
            t.u[1] = cvt_pk_bf16(v0.z, v0.w);
            t.u[2] = cvt_pk_bf16(v1.x, v1.y);
            t.u[3] = cvt_pk_bf16(v1.z, v1.w);
            afrag[kk] = t.v;
        }
    }

    asm volatile("s_waitcnt vmcnt(0) lgkmcnt(0)" ::: "memory");
    __builtin_amdgcn_s_barrier();

    const int bconst = (row16 << 6) + (kg << 4);    // conflict-free B-frag addr
    f32x4 acc0 = (f32x4)(0.0f);
    f32x4 acc1 = (f32x4)(0.0f);
    float p[4] = {};

    char* ba = (char*)Bs[0];                        // read buffer
    char* bb = (char*)Bs[1];                        // next read
    char* bc = (char*)Bs[2];                        // stage target

    // one phase (kq static): 8 ds_read + 8 MFMA vs chunk in ba; stage ph+2 -> bc
    #define PHASE(KQ_) do {                                                       \
        const int _ph = (uc << 2) + (KQ_);                                        \
        if (_ph < 62) stage(_ph + 2, bc);                                         \
        __builtin_amdgcn_s_setprio(1);                                            \
        _Pragma("unroll")                                                         \
        for (int _i = 0; _i < 4; ++_i) {                                          \
            bf16x8 _b0 = ld_bf16x8(ba, (_i << 11) + bconst);                      \
            bf16x8 _b1 = ld_bf16x8(ba, (_i << 11) + 1024 + bconst);               \
            acc0 = __builtin_amdgcn_mfma_f32_16x16x32_bf16(                       \
                       afrag[((KQ_) << 2) + _i], _b0, acc0, 0, 0, 0);             \
            acc1 = __builtin_amdgcn_mfma_f32_16x16x32_bf16(                       \
                       afrag[((KQ_) << 2) + _i], _b1, acc1, 0, 0, 0);             \
        }                                                                         \
        __builtin_amdgcn_s_setprio(0);                                            \
        if ((KQ_) == 3) {   /* u-chunk complete: tanh + V-dot */                  \
            const int _ub = uc << 5;                                              \
            float _qv0 = qbs[_ub + row16],      _vv0 = Vs[_ub + row16];           \
            float _qv1 = qbs[_ub + 16 + row16], _vv1 = Vs[_ub + 16 + row16];      \
            _Pragma("unroll")                                                     \
            for (int _r = 0; _r < 4; ++_r) {                                      \
                float _x0 = acc0[_r] + _qv0;                                      \
                float _e0 = exp2f(2.8853900817779268f * _x0);                     \
                float _t0 = 1.0f - 2.0f * __builtin_amdgcn_rcpf(_e0 + 1.0f);      \
                p[_r] = fmaf(_t0, _vv0, p[_r]);                                   \
                float _x1 = acc1[_r] + _qv1;                                      \
                float _e1 = exp2f(2.8853900817779268f * _x1);                     \
                float _t1 = 1.0f - 2.0f * __builtin_amdgcn_rcpf(_e1 + 1.0f);      \
                p[_r] = fmaf(_t1, _vv1, p[_r]);                                   \
            }                                                                     \
            acc0 = (f32x4)(0.0f); acc1 = (f32x4)(0.0f);                           \
        }                                                                         \
        if (_ph < 62)       { asm volatile("s_waitcnt vmcnt(2)" ::: "memory"); }  \
        else if (_ph == 62) { asm volatile("s_waitcnt vmcnt(0)" ::: "memory"); }  \
        if (_ph < 63) __builtin_amdgcn_s_barrier();                               \
        { char* _t = ba; ba = bb; bb = bc; bc = _t; }                             \
    } while (0)

    #pragma unroll 1
    for (int uc = 0; uc < 16; ++uc) {
        PHASE(0);
        PHASE(1);
        PHASE(2);
        PHASE(3);
    }
    #undef PHASE

    // reduce over the 16 u-lanes of each quarter-wave group
    #pragma unroll
    for (int r = 0; r < 4; ++r) {
        float v = p[r];
        v += __shfl_xor(v, 1);
        v += __shfl_xor(v, 2);
        v += __shfl_xor(v, 4);
        v += __shfl_xor(v, 8);
        p[r] = v;
    }
    if (row16 == 0) {
        float* srow = scores + ((size_t)(g * NB + b)) * NT + t0 + (wave << 4);
        #pragma unroll
        for (int r = 0; r < 4; ++r)
            srow[(kg << 2) + r] = p[r];             // C/D row = (lane>>4)*4 + reg
    }
}

// ---------- kernel 4: softmax over T + context, 4 d-slices per (g,b) ----------
__global__ __launch_bounds__(256) void finish_kernel(
    const float* __restrict__ scores, const float* __restrict__ bV,
    const float* __restrict__ values,
    float* __restrict__ out_ctx, float* __restrict__ out_w)
{
    __shared__ float sl[NT];
    __shared__ float red[16];
    __shared__ float cred[4][128];
    const int blk   = blockIdx.x;
    const int gb    = blk >> 2;                     // 0..95
    const int slice = blk & 3;                      // d-slice of 128
    const int tid = threadIdx.x;
    const int lane = tid & 63, wid = tid >> 6;
    const float bv = bV[gb >> 5];

    float s[4];
    #pragma unroll
    for (int j = 0; j < 4; ++j)
        s[j] = scores[(size_t)gb * NT + tid + 256 * j] + bv;

    float m = fmaxf(fmaxf(s[0], s[1]), fmaxf(s[2], s[3]));
    #pragma unroll
    for (int mask = 32; mask; mask >>= 1) m = fmaxf(m, __shfl_xor(m, mask));
    if (lane == 0) red[wid] = m;
    __syncthreads();
    const float gm = fmaxf(fmaxf(red[0], red[1]), fmaxf(red[2], red[3]));

    float e[4], ps = 0.f;
    #pragma unroll
    for (int j = 0; j < 4; ++j) { e[j] = __expf(s[j] - gm); ps += e[j]; }
    #pragma unroll
    for (int mask = 32; mask; mask >>= 1) ps += __shfl_xor(ps, mask);
    if (lane == 0) red[8 + wid] = ps;
    __syncthreads();
    const float inv = 1.f / (red[8] + red[9] + red[10] + red[11]);

    #pragma unroll
    for (int j = 0; j < 4; ++j) {
        float w = e[j] * inv;
        sl[tid + 256 * j] = w;
        if (slice == 0) out_w[(size_t)gb * NT + tid + 256 * j] = w;
    }
    __syncthreads();

    const int dp = tid & 63;
    const int tg = tid >> 6;
    const float* vbase = values + (size_t)gb * NT * ND + slice * 128 + dp * 2;
    float ax = 0.f, ay = 0.f;
    #pragma unroll 4
    for (int t = tg; t < NT; t += 4) {
        float2 v = *(const float2*)(vbase + (size_t)t * ND);
        float w = sl[t];
        ax = fmaf(w, v.x, ax);
        ay = fmaf(w, v.y, ay);
    }
    cred[tg][dp * 2]     = ax;
    cred[tg][dp * 2 + 1] = ay;
    __syncthreads();
    if (tid < 128) {
        float r = cred[0][tid] + cred[1][tid] + cred[2][tid] + cred[3][tid];
        out_ctx[(size_t)gb * ND + slice * 128 + tid] = r;
    }
}

extern "C" void kernel_launch(void* const* d_in, const int* in_sizes, int n_in,
                              void* d_out, int out_size, void* d_ws, size_t ws_size,
                              hipStream_t stream)
{
    (void)in_sizes; (void)n_in; (void)out_size; (void)ws_size;
    const float* query  = (const float*)d_in[0];
    const float* values = (const float*)d_in[1];
    const float* W1     = (const float*)d_in[2];
    const float* b1     = (const float*)d_in[3];
    const float* W2     = (const float*)d_in[4];
    const float* b2     = (const float*)d_in[5];
    const float* Vv     = (const float*)d_in[6];
    const float* bV     = (const float*)d_in[7];

    float* out_ctx = (float*)d_out;
    float* out_w   = out_ctx + (size_t)NG * NB * ND;

    // ws: qb (192 KiB) | scores (384 KiB) | w2t image (1.5 MiB)
    float* qb     = (float*)d_ws;
    float* scores = qb + (size_t)NG * NB * NU;
    char*  w2t    = (char*)(scores + (size_t)NG * NB * NT);

    prep_qb_kernel <<<NG * 8,            256, 0, stream>>>(query, W1, b1, b2, qb);
    prep_w2t_kernel<<<NG * 64,           256, 0, stream>>>(W2, w2t);
    score_kernel   <<<NG * NB * (NT/64), 256, 0, stream>>>(values, w2t, qb, Vv, scores);
    finish_kernel  <<<NG * NB * 4,       256, 0, stream>>>(scores, bV, values, out_ctx, out_w);
}